// Round 5
// baseline (16244.275 us; speedup 1.0000x reference)
//
#include <hip/hip_runtime.h>
#include <math.h>

// ESN recurrence: x_t = tanh(u_t @ w_in^T + w_bias + W @ h_{t-1}), h_0 = 0.
// B=8, T=4096, D_RES=1024, D_IN=64, fp32.
//
// 256 WGs (8 batches x 32 row-chunks) x 256 threads; 32x1024 W slab in regs.
// Sync v4 (R5). Lessons: R2 9.4ms (4 IC round-trips, tiny poll traffic);
// R3 11.9ms / R4 12.0ms (poll fan-in storms, 1-5 TB/s through the fabric).
// The knob that matters is POLL TRAFFIC, not hop count. R5:
//  - (value,tag) 8B atomic pairs carry h: no producer drain-ack; consumer's
//    load IS the validity check; pairs are loaded ONCE (self-validating,
//    per-element retry on the rare stale hit) -- never polled.
//  - Gate: 128 per-producer-wave flags per batch, DENSELY packed (8 cache
//    lines), stored with no drain (hint only -- pairs self-validate).
//  - Poll fan-in: ONE wave per WG polls the 8 flag lines (512 B/round);
//    waves 1-3 spin on an LDS go-word (zero fabric traffic).
//  - One __syncthreads/step (post-restage); its vmcnt drain covers stores
//    issued ~0.5us earlier -> acks already home -> ~free.
// Overwrite safety (2-slot pairs): wave W stores flag=t+1 only after its
// tag-t pair loads DELIVERED (data dep -> waitcnt precedes compute ->
// precedes flag store). Producer overwrites slot[(t+1)&1] only after seeing
// all 128 flags==t+1 => every reader of the overwritten pairs is done.
// Placement-independent: all exchange via agent-scope atomics.

#define NB        8
#define T_STEPS   4096
#define DRES      1024
#define DIN       64
#define CHUNKS    32
#define NTHREADS  256
#define NWAVES    4
#define FLAGS_PER_B (CHUNKS * NWAVES)   // 128

// ws layout: [pairs: 2*NB*DRES u64 = 128 KB][flags: NB*128 u32 = 4 KB]
#define PAIR_U64S   (2 * NB * DRES)
#define FLAG_OFFSET (PAIR_U64S * sizeof(unsigned long long))
#define FLAG_BYTES  (NB * FLAGS_PER_B * sizeof(unsigned int))
#define WS_BYTES    (FLAG_OFFSET + FLAG_BYTES)

__launch_bounds__(NTHREADS, 1)
__global__ void esn_kernel(const float* __restrict__ u,      // [NB][T][DIN]
                           const float* __restrict__ w_in,   // [DRES][DIN]
                           const float* __restrict__ w,      // [DRES][DRES]
                           const float* __restrict__ w_bias, // [DRES]
                           float* __restrict__ out,          // [NB][T][DRES]
                           unsigned long long* __restrict__ pairs, // [2][NB][DRES]
                           unsigned int* __restrict__ flags) // [NB][128]
{
    const int tid   = threadIdx.x;
    const int b     = blockIdx.x & (NB - 1);   // batch (XCD-affinity heuristic)
    const int chunk = blockIdx.x >> 3;         // 0..31 row-chunk
    const int rg    = tid >> 5;                // 0..7 row-group (4 rows each)
    const int mc    = tid & 31;                // 0..31 k-lane
    const int lane  = tid & 63;                // lane within wave
    const int wv    = tid >> 6;                // 0..3 wave id
    const int row0  = chunk * 32 + rg * 4;

    __shared__ float h_lds[2][DRES];
    __shared__ unsigned int go_word;

    // ---- prologue: weights into registers ----
    float wreg[4][32];                         // wreg[i][j] = W[row0+i][mc+32j]
    #pragma unroll
    for (int i = 0; i < 4; ++i) {
        const float* wr = w + (size_t)(row0 + i) * DRES + mc;
        #pragma unroll
        for (int j = 0; j < 32; ++j)
            wreg[i][j] = wr[32 * j];
    }
    float win0[4], win1[4];
    #pragma unroll
    for (int i = 0; i < 4; ++i) {
        win0[i] = w_in[(row0 + i) * DIN + 2 * mc];
        win1[i] = w_in[(row0 + i) * DIN + 2 * mc + 1];
    }
    float bias[4];
    #pragma unroll
    for (int i = 0; i < 4; ++i)
        bias[i] = w_bias[row0 + i];

    if (tid == 0) go_word = 0;
    #pragma unroll
    for (int k = tid; k < DRES; k += NTHREADS)
        h_lds[0][k] = 0.0f;
    __syncthreads();

    const float* ub = u + (size_t)b * T_STEPS * DIN;
    float2 ucur = *(const float2*)(ub + 2 * mc);

    unsigned int* fb = flags + b * FLAGS_PER_B;

    #pragma unroll 1
    for (int t = 0; t < T_STEPS; ++t) {
        const int tn = (t + 1 < T_STEPS) ? (t + 1) : t;
        const float2 unext = *(const float2*)(ub + (size_t)tn * DIN + 2 * mc);

        // ---- compute: input proj + register matvec (h bcast from LDS) ----
        const float* hl = h_lds[t & 1];
        float acc[4];
        #pragma unroll
        for (int i = 0; i < 4; ++i)
            acc[i] = fmaf(win0[i], ucur.x, win1[i] * ucur.y);
        #pragma unroll
        for (int j = 0; j < 32; ++j) {
            const float hv = hl[mc + 32 * j];
            #pragma unroll
            for (int i = 0; i < 4; ++i)
                acc[i] = fmaf(wreg[i][j], hv, acc[i]);
        }
        #pragma unroll
        for (int d = 1; d < 32; d <<= 1) {
            #pragma unroll
            for (int i = 0; i < 4; ++i)
                acc[i] += __shfl_xor(acc[i], d, 64);
        }
        float x[4];
        #pragma unroll
        for (int i = 0; i < 4; ++i) {
            const float z = acc[i] + bias[i];
            const float e = __expf(2.0f * z);
            x[i] = 1.0f - 2.0f / (e + 1.0f);
        }

        // ---- publish: (value, tag) pairs, then this wave's packed flag ----
        const unsigned int tag = (unsigned int)(t + 1);
        unsigned long long* pb = pairs + (size_t)(t & 1) * NB * DRES + (size_t)b * DRES;
        if (mc < 4) {
            const float v = (mc & 2) ? ((mc & 1) ? x[3] : x[2])
                                     : ((mc & 1) ? x[1] : x[0]);
            const unsigned long long pk =
                ((unsigned long long)tag << 32) | (unsigned long long)__float_as_uint(v);
            __hip_atomic_store(pb + row0 + mc, pk,
                               __ATOMIC_RELAXED, __HIP_MEMORY_SCOPE_AGENT);
        }
        if (lane == 0)   // hint only; pairs self-validate the data race
            __hip_atomic_store(fb + chunk * NWAVES + wv, tag,
                               __ATOMIC_RELAXED, __HIP_MEMORY_SCOPE_AGENT);

        // output store (off critical path)
        if (mc == 0) {
            *(float4*)(out + ((size_t)b * T_STEPS + t) * DRES + row0) =
                make_float4(x[0], x[1], x[2], x[3]);
        }
        ucur = unext;

        if (t + 1 == T_STEPS) break;

        // ---- gate: wave 0 polls the 8 dense flag lines; others spin on LDS ----
        if (wv == 0) {
            const unsigned int* fp = fb + 2 * lane;
            for (;;) {
                const unsigned int f0 =
                    __hip_atomic_load(fp + 0, __ATOMIC_RELAXED, __HIP_MEMORY_SCOPE_AGENT);
                const unsigned int f1 =
                    __hip_atomic_load(fp + 1, __ATOMIC_RELAXED, __HIP_MEMORY_SCOPE_AGENT);
                if (__ballot(f0 == tag && f1 == tag) == ~0ull) break;
                __builtin_amdgcn_s_sleep(1);
            }
            if (lane == 0)
                __hip_atomic_store(&go_word, tag,
                                   __ATOMIC_RELAXED, __HIP_MEMORY_SCOPE_WORKGROUP);
        } else {
            while (__hip_atomic_load(&go_word, __ATOMIC_RELAXED,
                                     __HIP_MEMORY_SCOPE_WORKGROUP) != tag)
                __builtin_amdgcn_s_sleep(1);
        }

        // ---- load pairs ONCE (self-validating; rare per-thread retry) ----
        // wave wv restages rows [wv*256, wv*256+256): row = wv*256 + i*64 + lane
        const unsigned long long* pp = pb + wv * 256 + lane;
        unsigned long long p0, p1, p2, p3;
        for (;;) {
            p0 = __hip_atomic_load(pp + 0,   __ATOMIC_RELAXED, __HIP_MEMORY_SCOPE_AGENT);
            p1 = __hip_atomic_load(pp + 64,  __ATOMIC_RELAXED, __HIP_MEMORY_SCOPE_AGENT);
            p2 = __hip_atomic_load(pp + 128, __ATOMIC_RELAXED, __HIP_MEMORY_SCOPE_AGENT);
            p3 = __hip_atomic_load(pp + 192, __ATOMIC_RELAXED, __HIP_MEMORY_SCOPE_AGENT);
            if ((unsigned int)(p0 >> 32) == tag && (unsigned int)(p1 >> 32) == tag &&
                (unsigned int)(p2 >> 32) == tag && (unsigned int)(p3 >> 32) == tag)
                break;
            __builtin_amdgcn_s_sleep(1);
        }
        float* hn = h_lds[(t + 1) & 1] + wv * 256 + lane;
        hn[0]   = __uint_as_float((unsigned int)p0);
        hn[64]  = __uint_as_float((unsigned int)p1);
        hn[128] = __uint_as_float((unsigned int)p2);
        hn[192] = __uint_as_float((unsigned int)p3);
        __syncthreads();   // restage->compute RAW; drains long-since-acked stores
    }
}

extern "C" void kernel_launch(void* const* d_in, const int* in_sizes, int n_in,
                              void* d_out, int out_size, void* d_ws, size_t ws_size,
                              hipStream_t stream) {
    const float* u      = (const float*)d_in[0];
    const float* w_in   = (const float*)d_in[1];
    const float* w      = (const float*)d_in[2];
    const float* w_bias = (const float*)d_in[3];
    float* out = (float*)d_out;

    unsigned long long* pairs = (unsigned long long*)d_ws;
    unsigned int* flags = (unsigned int*)((char*)d_ws + FLAG_OFFSET);

    // tags/flags must start < 1 (poison 0xAAAAAAAA never matches tags 1..4096,
    // but zero for determinism)
    hipMemsetAsync(d_ws, 0, WS_BYTES, stream);

    esn_kernel<<<NB * CHUNKS, NTHREADS, 0, stream>>>(u, w_in, w, w_bias, out,
                                                     pairs, flags);
}